// Round 4
// baseline (239.139 us; speedup 1.0000x reference)
//
#include <hip/hip_runtime.h>
#include <hip/hip_bf16.h>

// HorizonTemporalSelfAttention: multi-scale deformable attention
// bs=2, nq=16384, E=256, NH=8, NL=4, NP=4, d=32, total tokens=21760
//
// R4: f16 logits end-to-end, packed-f16 tap blend with per-level f32 flush,
//     GEMM M=64xN=128 tiles staging A and B from f32 (convert = value only).

typedef __attribute__((ext_vector_type(4))) float    float4v;
typedef __attribute__((ext_vector_type(8))) _Float16 half8;
typedef __attribute__((ext_vector_type(4))) _Float16 half4;
typedef __attribute__((ext_vector_type(2))) _Float16 half2v;

#define NQ    16384
#define NTOK  21760
#define NLOG  384

#define N_V4  2785280   // value f32 in float4 units

union H8 { half8 v; half2v p[4]; };

// ---------------- K1: convert value f32 -> f16 ----------------
__global__ __launch_bounds__(256) void convert_kernel(
    const float* __restrict__ val, _Float16* __restrict__ vh) {
  int i = blockIdx.x * 256 + threadIdx.x;
  float4v v = ((const float4v*)val)[i];
  half4 o;
  o[0] = (_Float16)v[0]; o[1] = (_Float16)v[1];
  o[2] = (_Float16)v[2]; o[3] = (_Float16)v[3];
  ((half4*)vh)[i] = o;
}

// ---------------- K2: LDS-staged fp16 MFMA GEMM, f16 logits out ----------------
// grid (512, 3): tile M=64 (bx), N=128 (by), K=256 in 4 chunks of 64.
// 4 waves 2x2 -> wave tile 32x64 = 2x4 subtiles of 16x16.
#define LDSTR 88
__global__ __launch_bounds__(256) void gemm_kernel(
    const float* __restrict__ qf,
    const float* __restrict__ Woff, const float* __restrict__ Wattn,
    const float* __restrict__ boff, const float* __restrict__ battn,
    _Float16* __restrict__ lh) {
  __shared__ _Float16 As[64 * LDSTR];
  __shared__ _Float16 Bs[128 * LDSTR];

  const int tid  = threadIdx.x;
  const int lane = tid & 63;
  const int wv   = tid >> 6;
  const int wm   = wv >> 1, wn = wv & 1;
  const int quad = lane >> 4;
  const int r    = lane & 15;
  const int blockM = blockIdx.x * 64;
  const int n0     = blockIdx.y * 128;

  float4v acc[2][4];
#pragma unroll
  for (int i = 0; i < 2; ++i)
#pragma unroll
    for (int j = 0; j < 4; ++j) acc[i][j] = (float4v){0.f, 0.f, 0.f, 0.f};

  for (int kc = 0; kc < 4; ++kc) {
    const int k0 = kc * 64;
    if (kc) __syncthreads();
    // A: 64 rows x 16 float4 k-cols, f32 -> f16
#pragma unroll
    for (int it = 0; it < 4; ++it) {
      int idx = it * 256 + tid;
      int row = idx >> 4, k4 = idx & 15;
      float4v v = *(const float4v*)(qf + (size_t)(blockM + row) * 256 + k0 + k4 * 4);
      half4 o;
      o[0] = (_Float16)v[0]; o[1] = (_Float16)v[1];
      o[2] = (_Float16)v[2]; o[3] = (_Float16)v[3];
      *(half4*)&As[row * LDSTR + k4 * 4] = o;
    }
    // B: 128 rows x 16 float4 k-cols, f32 -> f16 (row n0+row of Wcat)
#pragma unroll
    for (int it = 0; it < 8; ++it) {
      int idx = it * 256 + tid;
      int row = idx >> 4, k4 = idx & 15;
      int n = n0 + row;
      const float* src = (n < 256) ? (Woff + (size_t)n * 256)
                                   : (Wattn + (size_t)(n - 256) * 256);
      float4v v = *(const float4v*)(src + k0 + k4 * 4);
      half4 o;
      o[0] = (_Float16)v[0]; o[1] = (_Float16)v[1];
      o[2] = (_Float16)v[2]; o[3] = (_Float16)v[3];
      *(half4*)&Bs[row * LDSTR + k4 * 4] = o;
    }
    __syncthreads();

#pragma unroll
    for (int kf = 0; kf < 2; ++kf) {
      const int ko = kf * 32 + quad * 8;
      half8 af[2], bf[4];
#pragma unroll
      for (int mi = 0; mi < 2; ++mi)
        af[mi] = *(const half8*)&As[(wm * 32 + mi * 16 + r) * LDSTR + ko];
#pragma unroll
      for (int ni = 0; ni < 4; ++ni)
        bf[ni] = *(const half8*)&Bs[(wn * 64 + ni * 16 + r) * LDSTR + ko];
#pragma unroll
      for (int mi = 0; mi < 2; ++mi)
#pragma unroll
        for (int ni = 0; ni < 4; ++ni)
          acc[mi][ni] = __builtin_amdgcn_mfma_f32_16x16x32_f16(af[mi], bf[ni], acc[mi][ni], 0, 0, 0);
    }
  }

#pragma unroll
  for (int mi = 0; mi < 2; ++mi) {
    const int mb = blockM + wm * 32 + mi * 16 + quad * 4;
#pragma unroll
    for (int ni = 0; ni < 4; ++ni) {
      const int n = n0 + wn * 64 + ni * 16 + r;
      const float bias = (n < 256) ? boff[n] : battn[n - 256];
#pragma unroll
      for (int reg = 0; reg < 4; ++reg)
        lh[(size_t)(mb + reg) * NLOG + n] = (_Float16)(acc[mi][ni][reg] + bias);
    }
  }
}

// ---------------- K3: sampling (packed f16 blend, f16 logits) ----------------
// grid (256, 8, 2) = (q-tile of 64, head, batch); block 256.
// thread: c4 = tid&3 -> channels c4*8..c4*8+7 (half8 taps); qi = tid>>2.
__global__ __launch_bounds__(256) void sample_kernel(
    const _Float16* __restrict__ vh, const float* __restrict__ refp,
    const _Float16* __restrict__ lh, float* __restrict__ out) {
  const int qt = blockIdx.x, h = blockIdx.y, b = blockIdx.z;
  const int tid = threadIdx.x;
  const int c4 = tid & 3;
  const int qi = tid >> 2;
  const int q  = qt * 64 + qi;
  const size_t bq = (size_t)b * NQ + q;
  const _Float16* lg = lh + bq * NLOG;

  // offsets: 32 halves at h*32, layout l*8 + p*2 + xy
  float offf[32];
#pragma unroll
  for (int i = 0; i < 4; ++i) {
    half8 oh = *(const half8*)(lg + h * 32 + i * 8);
#pragma unroll
    for (int j = 0; j < 8; ++j) offf[i * 8 + j] = (float)oh[j];
  }
  // attn logits: 16 halves at 256 + h*16 -> softmax (f32)
  float al[16];
#pragma unroll
  for (int i = 0; i < 2; ++i) {
    half8 ah = *(const half8*)(lg + 256 + h * 16 + i * 8);
#pragma unroll
    for (int j = 0; j < 8; ++j) al[i * 8 + j] = (float)ah[j];
  }
  float mx = -1e30f;
#pragma unroll
  for (int i = 0; i < 16; ++i) mx = fmaxf(mx, al[i]);
  float ssum = 0.f;
#pragma unroll
  for (int i = 0; i < 16; ++i) {
    float e = __expf(al[i] - mx);
    al[i] = e;
    ssum += e;
  }
  const float inv = 1.0f / ssum;

  float4v rp0 = *(const float4v*)(refp + bq * 8);
  float4v rp1 = *(const float4v*)(refp + bq * 8 + 4);
  const float rpx[4] = {rp0[0], rp0[2], rp1[0], rp1[2]};
  const float rpy[4] = {rp0[1], rp0[3], rp1[1], rp1[3]};

  const _Float16* vb = vh + (size_t)b * NTOK * 256 + h * 32 + c4 * 8;
  float4v acc0 = (float4v){0.f, 0.f, 0.f, 0.f};
  float4v acc1 = (float4v){0.f, 0.f, 0.f, 0.f};

  const int base[4] = {0, 16384, 20480, 21504};

#pragma unroll
  for (int l = 0; l < 4; ++l) {
    const int   W  = 128 >> l;
    const float fW = (float)W;
    const _Float16* vlev = vb + (size_t)base[l] * 256;
    half2v accl[4];
#pragma unroll
    for (int j = 0; j < 4; ++j) accl[j] = (half2v){(_Float16)0, (_Float16)0};
#pragma unroll
    for (int p = 0; p < 4; ++p) {
      const float a  = al[l * 4 + p] * inv;
      const float ox = offf[l * 8 + p * 2];
      const float oy = offf[l * 8 + p * 2 + 1];
      // (ref + off/shape)*2-1 through grid_sample == ref*W + off - 0.5
      const float x = rpx[p] * fW + ox - 0.5f;
      const float y = rpy[p] * fW + oy - 0.5f;
      const float xf = floorf(x), yf = floorf(y);
      const float fx = x - xf, fy = y - yf;
      const int ix = (int)xf, iy = (int)yf;
      const int ix0 = min(max(ix, 0), W - 1);
      const int ix1 = min(max(ix + 1, 0), W - 1);
      const int iy0 = min(max(iy, 0), W - 1);
      const int iy1 = min(max(iy + 1, 0), W - 1);
      const float wx0 = ((unsigned)ix       < (unsigned)W) ? 1.f - fx : 0.f;
      const float wx1 = ((unsigned)(ix + 1) < (unsigned)W) ? fx       : 0.f;
      const float wy0 = ((unsigned)iy       < (unsigned)W) ? 1.f - fy : 0.f;
      const float wy1 = ((unsigned)(iy + 1) < (unsigned)W) ? fy       : 0.f;
      const _Float16 w00 = (_Float16)(a * wx0 * wy0);
      const _Float16 w01 = (_Float16)(a * wx1 * wy0);
      const _Float16 w10 = (_Float16)(a * wx0 * wy1);
      const _Float16 w11 = (_Float16)(a * wx1 * wy1);
      const half2v h00 = (half2v){w00, w00};
      const half2v h01 = (half2v){w01, w01};
      const half2v h10 = (half2v){w10, w10};
      const half2v h11 = (half2v){w11, w11};
      const _Float16* r0 = vlev + (size_t)(iy0 * W) * 256;
      const _Float16* r1 = vlev + (size_t)(iy1 * W) * 256;
      H8 t00, t01, t10, t11;
      t00.v = *(const half8*)(r0 + ix0 * 256);
      t01.v = *(const half8*)(r0 + ix1 * 256);
      t10.v = *(const half8*)(r1 + ix0 * 256);
      t11.v = *(const half8*)(r1 + ix1 * 256);
#pragma unroll
      for (int j = 0; j < 4; ++j) {
        accl[j] += h00 * t00.p[j] + h01 * t01.p[j]
                 + h10 * t10.p[j] + h11 * t11.p[j];
      }
    }
    // flush level accumulator to f32
    acc0[0] += (float)accl[0][0]; acc0[1] += (float)accl[0][1];
    acc0[2] += (float)accl[1][0]; acc0[3] += (float)accl[1][1];
    acc1[0] += (float)accl[2][0]; acc1[1] += (float)accl[2][1];
    acc1[2] += (float)accl[3][0]; acc1[3] += (float)accl[3][1];
  }

  // LDS transpose -> coalesced out[b][h*32+c][q]
  __shared__ float sm[32][65];
#pragma unroll
  for (int j = 0; j < 4; ++j) {
    sm[c4 * 8 + j][qi]     = acc0[j];
    sm[c4 * 8 + 4 + j][qi] = acc1[j];
  }
  __syncthreads();
  const size_t obase = ((size_t)b * 256 + h * 32) * NQ + qt * 64;
#pragma unroll
  for (int i = 0; i < 8; ++i) {
    const int idx = i * 256 + tid;
    const int c = idx >> 6, qq = idx & 63;
    out[obase + (size_t)c * NQ + qq] = sm[c][qq];
  }
}

extern "C" void kernel_launch(void* const* d_in, const int* in_sizes, int n_in,
                              void* d_out, int out_size, void* d_ws, size_t ws_size,
                              hipStream_t stream) {
  const float* query = (const float*)d_in[0];
  const float* value = (const float*)d_in[1];
  const float* refp  = (const float*)d_in[2];
  const float* Woff  = (const float*)d_in[3];
  const float* boff  = (const float*)d_in[4];
  const float* Wattn = (const float*)d_in[5];
  const float* battn = (const float*)d_in[6];
  float* out = (float*)d_out;

  char* ws = (char*)d_ws;
  _Float16* vh = (_Float16*)ws;                    // 22,282,240 B
  _Float16* lh = (_Float16*)(ws + 22282240);       // 25,165,824 B

  convert_kernel<<<10880, 256, 0, stream>>>(value, vh);
  gemm_kernel<<<dim3(512, 3), 256, 0, stream>>>(query, Woff, Wattn, boff, battn, lh);
  sample_kernel<<<dim3(256, 8, 2), 256, 0, stream>>>(vh, refp, lh, out);
}